// Round 12
// baseline (887.060 us; speedup 1.0000x reference)
//
#include <hip/hip_runtime.h>
#include <math.h>

#define S_N 3000
#define NCOLS 30000
#define SCHUNK 16
#define KTILES 938      // ceil(30000/32)
#define TPC 59          // tiles per chunk (16*59 = 944 >= 938)
#define PST 17          // P row stride (floats): odd -> conflict-free

typedef __bf16 v8bf __attribute__((ext_vector_type(8)));
typedef float v16f __attribute__((ext_vector_type(16)));
typedef float v4f __attribute__((ext_vector_type(4)));

__device__ __forceinline__ float sigm(float x) { return 1.0f / (1.0f + expf(-x)); }

__device__ __forceinline__ bool bet(float av, int ai, float bv, int bi) {
  return (av > bv) || (av == bv && ai < bi);
}

// streaming insert (candidates ascending by index): strict > == lax.top_k tie rule
template <int M>
__device__ __forceinline__ void insS(float (&v)[M], int (&ix)[M], float nv, int ni) {
  if (!(nv > v[M - 1])) return;
  bool b[M];
#pragma unroll
  for (int q = 0; q < M; q++) b[q] = nv > v[q];
#pragma unroll
  for (int q = M - 1; q > 0; q--) {
    v[q]  = b[q] ? (b[q - 1] ? v[q - 1] : nv) : v[q];
    ix[q] = b[q] ? (b[q - 1] ? ix[q - 1] : ni) : ix[q];
  }
  if (b[0]) { v[0] = nv; ix[0] = ni; }
}

// full comparator insert (value desc, index asc) for arbitrary-order merges
template <int M>
__device__ __forceinline__ void insF(float (&v)[M], int (&ix)[M], float nv, int ni) {
  if (!bet(nv, ni, v[M - 1], ix[M - 1])) return;
  bool b[M];
#pragma unroll
  for (int q = 0; q < M; q++) b[q] = bet(nv, ni, v[q], ix[q]);
#pragma unroll
  for (int q = M - 1; q > 0; q--) {
    v[q]  = b[q] ? (b[q - 1] ? v[q - 1] : nv) : v[q];
    ix[q] = b[q] ? (b[q - 1] ? ix[q - 1] : ni) : ix[q];
  }
  if (b[0]) { v[0] = nv; ix[0] = ni; }
}

__device__ __forceinline__ unsigned short f2bf_rne(float f) {
  unsigned int u = __float_as_uint(f);
  unsigned int r = (u + 0x7fffu + ((u >> 16) & 1u)) >> 16;
  return (unsigned short)r;
}
__device__ __forceinline__ float bf2f(unsigned short h) {
  return __uint_as_float(((unsigned int)h) << 16);
}

// ---------------------------------------------------------------------------
// Kernel 0: Whh third-split (ll) in fragment order, streamed by lstm per t.
// idx = frag*512 + lane*8 + j; frag = w*8 + tau*2 + s (w = wave 0..15).
// ---------------------------------------------------------------------------
__global__ __launch_bounds__(256) void cvt_wll(
    const float* __restrict__ Whh, unsigned short* __restrict__ Wllf)
{
  int idx = blockIdx.x * 256 + threadIdx.x;
  if (idx >= 128 * 512) return;
  int f = idx >> 9;
  int lane = (idx >> 3) & 63;
  int j = idx & 7;
  int w = f >> 3, tau = (f >> 1) & 3, s = f & 1;
  int kh = w >> 3, g8 = w & 7;
  int gate = g8 * 64 + tau * 16 + (lane & 15);
  int k = kh * 64 + s * 32 + (lane >> 4) * 8 + j;
  float x = Whh[gate * 128 + k];
  unsigned short hi = f2bf_rne(x);
  float r1 = x - bf2f(hi);
  unsigned short lo = f2bf_rne(r1);
  float r2 = r1 - bf2f(lo);
  Wllf[idx] = f2bf_rne(r2);
}

// ---------------------------------------------------------------------------
// Kernel 1: LSTM via MFMA (unchanged from R11 — dropped out of top-5).
// ---------------------------------------------------------------------------
__global__ __launch_bounds__(1024, 4) void lstm_kernel(
    const float* __restrict__ Xs, const float* __restrict__ Wih,
    const float* __restrict__ Whh, const float* __restrict__ bih,
    const float* __restrict__ bhh, const unsigned short* __restrict__ Wllf,
    float* __restrict__ H10)
{
  __shared__ float P[2 * 512 * PST];
  __shared__ __align__(16) __bf16 Asp[3][4][64][8];
  __shared__ float Xb[12 * 240];
  __shared__ float2 WB2[14][128];

  const int tid = threadIdx.x;
  const int s0 = blockIdx.x * 12;
  const int lane = tid & 63;
  const int wv = tid >> 6;
  const int kh = wv >> 3;
  const int g8 = wv & 7;
  const int l15 = lane & 15, lq = lane >> 4;

  for (int i = tid; i < 12 * 240; i += 1024) Xb[i] = Xs[(size_t)s0 * 240 + i];
  for (int i = tid; i < 3 * 4 * 64 * 8; i += 1024)
    ((unsigned short*)Asp)[i] = 0;
  for (int i = tid; i < 14 * 128; i += 1024) {
    int q = i >> 7, n = i & 127;
    float vv[2];
#pragma unroll
    for (int e = 0; e < 2; e++) {
      int r = 2 * q + e;
      if (r < 24) {
        int gate = n + (r / 6) * 128;
        vv[e] = Wih[gate * 6 + r % 6];
      } else {
        int gate = n + (r - 24) * 128;
        vv[e] = bih[gate] + bhh[gate];
      }
    }
    WB2[q][n] = make_float2(vv[0], vv[1]);
  }

  v8bf whi[4][2], wlo[4][2];
#pragma unroll
  for (int tau = 0; tau < 4; tau++)
#pragma unroll
    for (int s = 0; s < 2; s++) {
      int gate = g8 * 64 + tau * 16 + l15;
      int k0 = kh * 64 + s * 32 + lq * 8;
      const float* wp = Whh + gate * 128 + k0;
      v8bf h8, l8;
#pragma unroll
      for (int j = 0; j < 8; j++) {
        float x = wp[j];
        __bf16 bh_ = (__bf16)x;
        float r1 = x - (float)bh_;
        __bf16 bl_ = (__bf16)r1;
        h8[j] = bh_;
        l8[j] = bl_;
      }
      whi[tau][s] = h8;
      wlo[tau][s] = l8;
    }

  const unsigned short* wllbase = Wllf + (size_t)(wv * 8) * 512 + lane * 8;

  float c0 = 0.0f, c1 = 0.0f;
  const int p2n = tid & 127;
  const int p2m = tid >> 7;

  __syncthreads();

#pragma unroll 1
  for (int t = 0; t < 40; t++) {
    v8bf ah[2], al[2], a3[2];
#pragma unroll
    for (int s = 0; s < 2; s++) {
      int ks = kh * 2 + s;
      ah[s] = *(const v8bf*)&Asp[0][ks][lane][0];
      al[s] = *(const v8bf*)&Asp[1][ks][lane][0];
      a3[s] = *(const v8bf*)&Asp[2][ks][lane][0];
    }
#pragma unroll
    for (int tau = 0; tau < 4; tau++) {
      v4f acc = {0.0f, 0.0f, 0.0f, 0.0f};
#pragma unroll
      for (int s = 0; s < 2; s++) {
        v8bf wll = *(const v8bf*)(wllbase + (tau * 2 + s) * 512);
        acc = __builtin_amdgcn_mfma_f32_16x16x32_bf16(ah[s], whi[tau][s], acc, 0, 0, 0);
        acc = __builtin_amdgcn_mfma_f32_16x16x32_bf16(ah[s], wlo[tau][s], acc, 0, 0, 0);
        acc = __builtin_amdgcn_mfma_f32_16x16x32_bf16(al[s], whi[tau][s], acc, 0, 0, 0);
        acc = __builtin_amdgcn_mfma_f32_16x16x32_bf16(al[s], wlo[tau][s], acc, 0, 0, 0);
        acc = __builtin_amdgcn_mfma_f32_16x16x32_bf16(ah[s], wll, acc, 0, 0, 0);
        acc = __builtin_amdgcn_mfma_f32_16x16x32_bf16(a3[s], whi[tau][s], acc, 0, 0, 0);
      }
      if (lq < 3) {
        int gate = g8 * 64 + tau * 16 + l15;
        float* pp = P + kh * (512 * PST) + gate * PST + lq * 4;
#pragma unroll
        for (int reg = 0; reg < 4; reg++) pp[reg] = acc[reg];
      }
    }
    __syncthreads();

#pragma unroll
    for (int task = 0; task < 2; task++) {
      if (task == 1 && tid >= 512) break;
      const int m = task == 0 ? p2m : 8 + p2m;
      const int n = p2n;
      float wb[28];
#pragma unroll
      for (int q = 0; q < 14; q++) {
        float2 v = WB2[q][n];
        wb[2 * q] = v.x;
        wb[2 * q + 1] = v.y;
      }
      const float* xm = Xb + m * 240 + t * 6;
      float xv[6];
#pragma unroll
      for (int f = 0; f < 6; f++) xv[f] = xm[f];
      float g4[4];
#pragma unroll
      for (int g = 0; g < 4; g++) {
        float a = wb[24 + g];
#pragma unroll
        for (int f = 0; f < 6; f++) a = fmaf(wb[g * 6 + f], xv[f], a);
        int gate = n + g * 128;
        a += P[gate * PST + m] + P[512 * PST + gate * PST + m];
        g4[g] = a;
      }
      float& c = task == 0 ? c0 : c1;
      c = sigm(g4[1]) * c + sigm(g4[0]) * tanhf(g4[2]);
      float h = sigm(g4[3]) * tanhf(c);
      if (t >= 30) H10[((size_t)(s0 + m) * 10 + (t - 30)) * 128 + n] = h;
      __bf16 hh = (__bf16)h;
      float r1 = h - (float)hh;
      __bf16 hl = (__bf16)r1;
      float r2 = r1 - (float)hl;
      __bf16 h3 = (__bf16)r2;
      int ks = n >> 5, li = m + 16 * ((n >> 3) & 3), j = n & 7;
      Asp[0][ks][li][j] = hh;
      Asp[1][ks][li][j] = hl;
      Asp[2][ks][li][j] = h3;
    }
    __syncthreads();
  }
}

// ---------------------------------------------------------------------------
// Kernel 2a: LayerNorm in-place (unchanged).
// ---------------------------------------------------------------------------
__global__ __launch_bounds__(256) void ln_kernel(
    float* __restrict__ H, const float* __restrict__ g,
    const float* __restrict__ b, int nrows)
{
  int row = blockIdx.x * 4 + (threadIdx.x >> 6);
  int lane = threadIdx.x & 63;
  if (row >= nrows) return;
  float* hr = H + (size_t)row * 128;
  float x0 = hr[lane], x1 = hr[lane + 64];
  float s = x0 + x1;
  for (int off = 32; off > 0; off >>= 1) s += __shfl_xor(s, off);
  float mean = s * (1.0f / 128.0f);
  float d0 = x0 - mean, d1 = x1 - mean;
  float v = d0 * d0 + d1 * d1;
  for (int off = 32; off > 0; off >>= 1) v += __shfl_xor(v, off);
  float rstd = 1.0f / sqrtf(v * (1.0f / 128.0f) + 1e-5f);
  hr[lane] = d0 * rstd * g[lane] + b[lane];
  hr[lane + 64] = d1 * rstd * g[lane + 64] + b[lane + 64];
}

// ---------------------------------------------------------------------------
// Kernel 2b: Out[r] = l2norm(In_row[r] @ W^T) (unchanged).
// ---------------------------------------------------------------------------
__global__ __launch_bounds__(256) void proj_kernel(
    const float* __restrict__ In, int inOff, int inStride, int nr,
    const float* __restrict__ W, float* __restrict__ Out)
{
  __shared__ float A_s[16 * 128];
  const int tid = threadIdx.x;
  const int r0 = blockIdx.x * 16;

  for (int i = tid; i < 16 * 32; i += 256) {
    int row = i >> 5, c = i & 31;
    int gr = r0 + row;
    float4 v = make_float4(0.f, 0.f, 0.f, 0.f);
    if (gr < nr)
      v = *(const float4*)(In + (size_t)inOff + (size_t)gr * inStride + c * 4);
    *(float4*)(A_s + row * 128 + c * 4) = v;
  }
  __syncthreads();

  const int j = tid & 127, rh = tid >> 7;
  const float* wrow = W + j * 128;
  float acc[8] = {0, 0, 0, 0, 0, 0, 0, 0};
  for (int kc = 0; kc < 32; kc++) {
    float4 wv4 = *(const float4*)(wrow + kc * 4);
#pragma unroll
    for (int i = 0; i < 8; i++) {
      float4 a4 = *(const float4*)(A_s + (rh * 8 + i) * 128 + kc * 4);
      acc[i] = fmaf(wv4.x, a4.x, acc[i]);
      acc[i] = fmaf(wv4.y, a4.y, acc[i]);
      acc[i] = fmaf(wv4.z, a4.z, acc[i]);
      acc[i] = fmaf(wv4.w, a4.w, acc[i]);
    }
  }
  __syncthreads();
#pragma unroll
  for (int i = 0; i < 8; i++) A_s[(rh * 8 + i) * 128 + j] = acc[i];
  __syncthreads();

  const int r = tid >> 4, qq = tid & 15;
  float ss = 0.0f;
#pragma unroll
  for (int i = 0; i < 8; i++) {
    float u = A_s[r * 128 + qq + i * 16];
    ss += u * u;
  }
  for (int off = 8; off > 0; off >>= 1) ss += __shfl_xor(ss, off);
  float scale = 1.0f / fmaxf(sqrtf(ss), 1e-12f);
  int gr = r0 + r;
  if (gr < nr) {
#pragma unroll
    for (int i = 0; i < 8; i++)
      Out[(size_t)gr * 128 + qq + i * 16] = A_s[r * 128 + qq + i * 16] * scale;
  }
}

// ---------------------------------------------------------------------------
// Kernel 2c-Q: fp32 -> (bf16 hi, bf16 lo) split, linear layout (Q only).
// ---------------------------------------------------------------------------
__global__ __launch_bounds__(256) void cvt_kernel(
    const float* __restrict__ src, unsigned short* __restrict__ hi,
    unsigned short* __restrict__ lo, int n4)
{
  int i = blockIdx.x * 256 + threadIdx.x;
  if (i >= n4) return;
  float4 f = ((const float4*)src)[i];
  ushort4 h, l;
  h.x = f2bf_rne(f.x); l.x = f2bf_rne(f.x - bf2f(h.x));
  h.y = f2bf_rne(f.y); l.y = f2bf_rne(f.y - bf2f(h.y));
  h.z = f2bf_rne(f.z); l.z = f2bf_rne(f.z - bf2f(h.z));
  h.w = f2bf_rne(f.w); l.w = f2bf_rne(f.w - bf2f(h.w));
  ((ushort4*)hi)[i] = h;
  ((ushort4*)lo)[i] = l;
}

// ---------------------------------------------------------------------------
// Kernel 2c-K: fp32 K -> blocked bf16 hi/lo for coalesced score loads.
// idx = tile*4096 + s*512 + half*256 + r*8 + e; col = s*16+half*8+e, r=row%32.
// ---------------------------------------------------------------------------
__global__ __launch_bounds__(256) void cvt_blockK(
    const float* __restrict__ Kn, unsigned short* __restrict__ hi,
    unsigned short* __restrict__ lo)
{
  const int tile = blockIdx.x;
  const int tid = threadIdx.x;
#pragma unroll
  for (int jj = 0; jj < 4; jj++) {
    int i = tid + jj * 256;
    int r = i >> 5;
    int c0 = (i & 31) * 4;
    int row = tile * 32 + r;
    if (row >= NCOLS) continue;
    float4 f = *(const float4*)(Kn + (size_t)row * 128 + c0);
    ushort4 h, l;
    h.x = f2bf_rne(f.x); l.x = f2bf_rne(f.x - bf2f(h.x));
    h.y = f2bf_rne(f.y); l.y = f2bf_rne(f.y - bf2f(h.y));
    h.z = f2bf_rne(f.z); l.z = f2bf_rne(f.z - bf2f(h.z));
    h.w = f2bf_rne(f.w); l.w = f2bf_rne(f.w - bf2f(h.w));
    int s = c0 >> 4, half = (c0 >> 3) & 1, e = c0 & 7;
    size_t idx = (size_t)tile * 4096 + s * 512 + half * 256 + r * 8 + e;
    *(ushort4*)(hi + idx) = h;
    *(ushort4*)(lo + idx) = l;
  }
}

// ---------------------------------------------------------------------------
// Kernel 3: MFMA score + per-chunk approx top-8. R12: Q fragments staged in
// LDS fragment-order (16 KB) instead of 64 PINNED VGPRs — R11's pin left
// ~20 regs for 32 accumulator regs -> scratch spill (WRITE_SIZE 120 MB).
// Per k-step the B-operands are lane-distributed conflict-free ds_read_b128.
// acc1 split into two accumulators (dependent MFMA chain 16 -> 8); only the
// ~2^-9 correction term's summation order changes (exact rescore follows).
// launch_bounds(256,4): no min-occupancy pressure to shrink the budget.
// ---------------------------------------------------------------------------
__global__ __launch_bounds__(256, 4) void score_mfma(
    const unsigned short* __restrict__ Qh, const unsigned short* __restrict__ Ql,
    const unsigned short* __restrict__ Kh, const unsigned short* __restrict__ Kl,
    const int* __restrict__ tix, const float* __restrict__ log_temp,
    const float* __restrict__ lag_bias, float* __restrict__ part)
{
  __shared__ float lagS[16];
  __shared__ __align__(16) unsigned short Qs[2][8][64][8];   // 16 KB
  __shared__ float M[256 * 16];                              // 16 KB
  const int tid = threadIdx.x;
  const int wv = tid >> 6, lane = tid & 63;
  const int half = lane >> 5, tcol = lane & 31;
  const int chunk = blockIdx.y;
  const int T0 = blockIdx.x * 32;
  const int tstart = chunk * TPC;
  const int tend = (tstart + TPC < KTILES) ? tstart + TPC : KTILES;

  if (tid < 10) lagS[tid] = lag_bias[tid];

  const int tgt = T0 + tcol;
  const int tgtc = tgt < S_N ? tgt : S_N - 1;
  const int myTix = tix[tgtc];
  const float invtemp =
      1.0f / fminf(fmaxf(expf(log_temp[0]), 0.1f), 11.313708499f);

  // ---- stage Q fragments (hi+lo) into LDS in fragment order ----
  // chunk i = (split, s, laneq): 16B each; src = Q*[tix[T0+tcolq]*128
  // + halfq*8 + s*16 .. +8); dst = Qs[split][s][laneq][0..8).
  for (int i = tid; i < 1024; i += 256) {
    int split = i >> 9;
    int s = (i >> 6) & 7;
    int lq2 = i & 63;
    int halfq = lq2 >> 5, tcq = lq2 & 31;
    int tq = T0 + tcq;
    int src = tix[tq < S_N ? tq : S_N - 1];
    const unsigned short* sp =
        (split ? Ql : Qh) + (size_t)src * 128 + halfq * 8 + s * 16;
    *(uint4*)&Qs[split][s][lq2][0] = *(const uint4*)sp;
  }

  float tv[8]; int ti[8];
#pragma unroll
  for (int q = 0; q < 8; q++) { tv[q] = -3e38f; ti[q] = 0x7fffffff; }

  __syncthreads();   // Qs + lagS ready

  for (int it = 0; it < 15; it++) {
    const int tile = tstart + it * 4 + wv;
    const int tilec = tile < KTILES ? tile : KTILES - 1;
    const size_t ao = (size_t)tilec * 4096 + half * 256 + tcol * 8;

    v16f acc0, acc1a, acc1b;
#pragma unroll
    for (int q = 0; q < 16; q++) { acc0[q] = 0.0f; acc1a[q] = 0.0f; acc1b[q] = 0.0f; }

#pragma unroll
    for (int s = 0; s < 8; s++) {
      v8bf ah = *(const v8bf*)(Kh + ao + s * 512);
      v8bf al = *(const v8bf*)(Kl + ao + s * 512);
      v8bf qh8 = *(const v8bf*)&Qs[0][s][lane][0];
      v8bf ql8 = *(const v8bf*)&Qs[1][s][lane][0];
      acc0  = __builtin_amdgcn_mfma_f32_32x32x16_bf16(ah, qh8, acc0, 0, 0, 0);
      acc1a = __builtin_amdgcn_mfma_f32_32x32x16_bf16(ah, ql8, acc1a, 0, 0, 0);
      acc1b = __builtin_amdgcn_mfma_f32_32x32x16_bf16(al, qh8, acc1b, 0, 0, 0);
    }

    const int cb = tile * 32;
    const bool act = tile < tend;
#pragma unroll
    for (int reg = 0; reg < 16; reg++) {
      const int row = (reg & 3) + 8 * (reg >> 2) + 4 * half;
      const int col = cb + row;
      if (act && col < NCOLS) {
        const int s = col / 10;
        const int lag = col - s * 10;
        if (s != myTix) {
          float vsc =
              (acc0[reg] + (acc1a[reg] + acc1b[reg])) * invtemp + lagS[lag];
          insS<8>(tv, ti, vsc, col);
        }
      }
    }
  }

  {
    float* my = M + tid * 16;
#pragma unroll
    for (int q = 0; q < 8; q++) {
      my[2 * q] = tv[q];
      my[2 * q + 1] = __int_as_float(ti[q]);
    }
  }
  __syncthreads();
  if (tid < 32 && T0 + tid < S_N) {
    float v[8]; int ix[8];
#pragma unroll
    for (int q = 0; q < 8; q++) { v[q] = -3e38f; ix[q] = 0x7fffffff; }
    for (int w = 0; w < 8; w++) {
      const float* src = M + (w * 32 + tid) * 16;
#pragma unroll
      for (int q = 0; q < 8; q++)
        insF<8>(v, ix, src[2 * q], __float_as_int(src[2 * q + 1]));
    }
    float* dst = part + ((size_t)(T0 + tid) * SCHUNK + chunk) * 16;
#pragma unroll
    for (int q = 0; q < 8; q++) {
      dst[2 * q] = v[q];
      dst[2 * q + 1] = __int_as_float(ix[q]);
    }
  }
}

// ---------------------------------------------------------------------------
// Kernel 4: merge chunks -> approx top-8, exact fp32 rescore -> exact top-5,
// softmax, gather z, MLP (unchanged).
// ---------------------------------------------------------------------------
__global__ __launch_bounds__(256) void final_kernel(
    const float* __restrict__ part, const float* __restrict__ Qn,
    const float* __restrict__ Kn, const int* __restrict__ tix,
    const float* __restrict__ log_temp, const float* __restrict__ lag_bias,
    const float* __restrict__ Xraw,
    const float* __restrict__ W1, const float* __restrict__ b1,
    const float* __restrict__ W2, const float* __restrict__ b2,
    const float* __restrict__ W3, const float* __restrict__ b3,
    float* __restrict__ out)
{
  __shared__ float W1s[64 * 12];
  __shared__ float W2s[32 * 64];
  __shared__ float b1s[64];
  __shared__ float b2s[32];
  __shared__ float W3s[32];
  const int tid = threadIdx.x;
  for (int i = tid; i < 768; i += 256) W1s[i] = W1[i];
  for (int i = tid; i < 2048; i += 256) W2s[i] = W2[i];
  if (tid < 64) b1s[tid] = b1[tid];
  if (tid < 32) { b2s[tid] = b2[tid]; W3s[tid] = W3[tid]; }
  __syncthreads();

  int t = blockIdx.x * 256 + tid;
  if (t >= S_N) return;

  float av[8]; int ai[8];
#pragma unroll
  for (int q = 0; q < 8; q++) { av[q] = -3e38f; ai[q] = 0x7fffffff; }
  const float* pp = part + (size_t)t * (SCHUNK * 16);
  for (int c = 0; c < SCHUNK * 8; c++)
    insF<8>(av, ai, pp[2 * c], __float_as_int(pp[2 * c + 1]));

  const float invtemp =
      1.0f / fminf(fmaxf(expf(log_temp[0]), 0.1f), 11.313708499f);
  const float* q = Qn + (size_t)tix[t] * 128;
  const float* kr[8];
#pragma unroll
  for (int j = 0; j < 8; j++) kr[j] = Kn + (size_t)ai[j] * 128;
  float d[8] = {0, 0, 0, 0, 0, 0, 0, 0};
  for (int kc = 0; kc < 32; kc++) {
    float4 q4 = ((const float4*)q)[kc];
#pragma unroll
    for (int j = 0; j < 8; j++) {
      float4 k4 = ((const float4*)kr[j])[kc];
      d[j] = fmaf(q4.x, k4.x, d[j]);
      d[j] = fmaf(q4.y, k4.y, d[j]);
      d[j] = fmaf(q4.z, k4.z, d[j]);
      d[j] = fmaf(q4.w, k4.w, d[j]);
    }
  }

  float v[5]; int ix[5];
#pragma unroll
  for (int qq = 0; qq < 5; qq++) { v[qq] = -3e38f; ix[qq] = 0x7fffffff; }
#pragma unroll
  for (int j = 0; j < 8; j++) {
    int c = ai[j];
    int s = c / 10;
    int lag = c - 10 * s;
    float ev = d[j] * invtemp + lag_bias[lag];
    insF<5>(v, ix, ev, c);
  }

  float e1 = expf(v[1] - v[0]), e2 = expf(v[2] - v[0]),
        e3 = expf(v[3] - v[0]), e4 = expf(v[4] - v[0]);
  float rs = 1.0f / (1.0f + e1 + e2 + e3 + e4);
  float w_[5] = {rs, e1 * rs, e2 * rs, e3 * rs, e4 * rs};

  float feat[12];
#pragma unroll
  for (int f = 0; f < 12; f++) feat[f] = 0.0f;
#pragma unroll
  for (int qq = 0; qq < 5; qq++) {
    int iq = ix[qq];
    int s = iq / 10;
    int l = iq - 10 * s;
    int pos = 29 + l;
    const float* zp = Xraw + (size_t)s * 240 + pos * 6;
#pragma unroll
    for (int f = 0; f < 6; f++) {
      float z = zp[f];
      feat[f] += w_[qq] * z;
      if (qq == 0) feat[6 + f] = z;
    }
  }

  float h1[64];
#pragma unroll 4
  for (int o = 0; o < 64; o++) {
    float acc = b1s[o];
    const float* wr = W1s + o * 12;
#pragma unroll
    for (int f = 0; f < 12; f++) acc = fmaf(wr[f], feat[f], acc);
    h1[o] = fmaxf(acc, 0.0f);
  }
  float rr = b3[0];
#pragma unroll 2
  for (int o = 0; o < 32; o++) {
    float acc = b2s[o];
    const float* wr = W2s + o * 64;
#pragma unroll 8
    for (int k = 0; k < 64; k++) acc = fmaf(wr[k], h1[k], acc);
    rr = fmaf(W3s[o], fmaxf(acc, 0.0f), rr);
  }
  out[t] = rr;
}

// ---------------------------------------------------------------------------
extern "C" void kernel_launch(void* const* d_in, const int* in_sizes, int n_in,
                              void* d_out, int out_size, void* d_ws,
                              size_t ws_size, hipStream_t stream) {
  const float* Xs   = (const float*)d_in[0];
  const float* Xraw = (const float*)d_in[1];
  const int*   tix  = (const int*)d_in[2];
  const float* Wih  = (const float*)d_in[3];
  const float* Whh  = (const float*)d_in[4];
  const float* bih  = (const float*)d_in[5];
  const float* bhh  = (const float*)d_in[6];
  const float* ln_g = (const float*)d_in[7];
  const float* ln_b = (const float*)d_in[8];
  const float* WQ   = (const float*)d_in[9];
  const float* WK   = (const float*)d_in[10];
  const float* log_temp = (const float*)d_in[11];
  const float* lag_bias = (const float*)d_in[12];
  const float* W1 = (const float*)d_in[13];
  const float* b1 = (const float*)d_in[14];
  const float* W2 = (const float*)d_in[15];
  const float* b2 = (const float*)d_in[16];
  const float* W3 = (const float*)d_in[17];
  const float* b3 = (const float*)d_in[18];
  float* outp = (float*)d_out;

  float* ws = (float*)d_ws;
  float* H10 = ws;                                          // [0, 3.84M)
  unsigned short* Khi = (unsigned short*)ws;                // overlays H10
  unsigned short* Klo = (unsigned short*)(ws + 1922000);
  float* Kn  = ws + 3850000;
  float* Qn  = ws + 7690000;
  unsigned short* Qhi = (unsigned short*)(ws + 8074000);
  unsigned short* Qlo = (unsigned short*)(ws + 8266000);
  float* part = ws + 8458000;                               // 768000 fl
  unsigned short* Wllf = (unsigned short*)(ws + 9226000);   // 65536 us

  cvt_wll<<<256, 256, 0, stream>>>(Whh, Wllf);
  lstm_kernel<<<250, 1024, 0, stream>>>(Xs, Wih, Whh, bih, bhh, Wllf, H10);
  ln_kernel<<<7500, 256, 0, stream>>>(H10, ln_g, ln_b, 30000);
  proj_kernel<<<1875, 256, 0, stream>>>(H10, 0, 128, 30000, WK, Kn);
  proj_kernel<<<188, 256, 0, stream>>>(H10, 9 * 128, 1280, 3000, WQ, Qn);
  cvt_blockK<<<KTILES, 256, 0, stream>>>(Kn, Khi, Klo);
  cvt_kernel<<<375, 256, 0, stream>>>(Qn, Qhi, Qlo, 96000);
  {
    dim3 grid(94, SCHUNK);
    score_mfma<<<grid, 256, 0, stream>>>(Qhi, Qlo, Khi, Klo, tix, log_temp,
                                         lag_bias, part);
  }
  final_kernel<<<12, 256, 0, stream>>>(part, Qn, Kn, tix, log_temp, lag_bias,
                                       Xraw, W1, b1, W2, b2, W3, b3, outp);
}